// Round 4
// baseline (1181.322 us; speedup 1.0000x reference)
//
#include <hip/hip_runtime.h>
#include <hip/hip_bf16.h>

// AxialSelfAttention: B=32, N=2048 tokens, E=512.
// qkv = x@W+b ; out = rowAttn(q,k,v) + colAttn(q,k,v)
// All heavy GEMMs in bf16 MFMA (16x16x32), fp32 accumulate, fused epilogues.

#define NTOK 2048L
#define EDIM 512L
#define QKVD 1536L
#define BATCH 32L

typedef unsigned short u16;
typedef short s16x8 __attribute__((ext_vector_type(8)));
typedef float f32x4 __attribute__((ext_vector_type(4)));
typedef u16 u16x4 __attribute__((ext_vector_type(4)));
typedef u16 u16x8 __attribute__((ext_vector_type(8)));

__device__ __forceinline__ u16 f2bf(float f) {
  unsigned u = __float_as_uint(f);
  u += 0x7FFFu + ((u >> 16) & 1u);   // RNE (inputs finite)
  return (u16)(u >> 16);
}

__device__ __forceinline__ void gload16(const u16* g, u16* l) {
  __builtin_amdgcn_global_load_lds((__attribute__((address_space(1))) void*)(g),
                                   (__attribute__((address_space(3))) void*)(l),
                                   16, 0, 0);
}

enum { EPI_BIAS = 0, EPI_EXPSUM = 1, EPI_STF32 = 2, EPI_ADDDIV = 3 };

// C[M,N] = A[M,K] * B[N,K]^T  (bf16 in, fp32 acc), 128x128 tile, 4 waves.
template<int EPI>
__global__ __launch_bounds__(256, 2)
void gemm_bt(const u16* __restrict__ A, long lda, long sA,
             const u16* __restrict__ B, long ldb, long sB,
             void* __restrict__ Cv, long ldc, long sC,
             const float* __restrict__ bias,
             float* __restrict__ lrow, long sL,
             float alpha, int K)
{
  const int g = blockIdx.z;
  A += (long)g * sA;
  B += (long)g * sB;
  const int tid  = threadIdx.x;
  const int lane = tid & 63;
  const int w = tid >> 6, wr = w >> 1, wc = w & 1;
  const long brow = (long)blockIdx.y * 128;
  const long bcol = (long)blockIdx.x * 128;

  __shared__ __align__(16) u16 As[128 * 32];
  __shared__ __align__(16) u16 Bs[128 * 32];

  f32x4 acc[4][4] = {};

  // staging: 256 threads x 16B, two shots per tile (rows 0..63, 64..127)
  const int sr = tid >> 2;
  const int sc = (tid & 3) * 8;
  const u16* Ag0 = A + (brow + sr) * lda + sc;
  const u16* Ag1 = A + (brow + 64 + sr) * lda + sc;
  const u16* Bg0 = B + (bcol + sr) * ldb + sc;
  const u16* Bg1 = B + (bcol + 64 + sr) * ldb + sc;
  u16* As0 = As + tid * 8;        // linear: (tid>>2)*32 + (tid&3)*8 == tid*8
  u16* As1 = As + 2048 + tid * 8;
  u16* Bs0 = Bs + tid * 8;
  u16* Bs1 = Bs + 2048 + tid * 8;

  const int fr = lane & 15, fq = lane >> 4;
  const int nk = K >> 5;
  for (int kt = 0; kt < nk; ++kt) {
    __syncthreads();                       // protect LDS from prev compute
    gload16(Ag0, As0); gload16(Ag1, As1);
    gload16(Bg0, Bs0); gload16(Bg1, Bs1);
    Ag0 += 32; Ag1 += 32; Bg0 += 32; Bg1 += 32;
    __syncthreads();                       // vmcnt(0) drain + barrier
    s16x8 af[4], bfr[4];
#pragma unroll
    for (int m = 0; m < 4; ++m)
      af[m] = *(const s16x8*)(As + (wr * 64 + m * 16 + fr) * 32 + fq * 8);
#pragma unroll
    for (int n = 0; n < 4; ++n)
      bfr[n] = *(const s16x8*)(Bs + (wc * 64 + n * 16 + fr) * 32 + fq * 8);
#pragma unroll
    for (int m = 0; m < 4; ++m)
#pragma unroll
      for (int n = 0; n < 4; ++n)
        acc[m][n] = __builtin_amdgcn_mfma_f32_16x16x32_bf16(af[m], bfr[n], acc[m][n], 0, 0, 0);
  }

  const long crow0 = brow + wr * 64 + fq * 4;
  const long ccol0 = bcol + wc * 64 + fr;

  if constexpr (EPI == EPI_BIAS) {
    u16* C = (u16*)Cv + (long)g * sC;
#pragma unroll
    for (int m = 0; m < 4; ++m)
#pragma unroll
      for (int j = 0; j < 4; ++j) {
        long row = crow0 + m * 16 + j;
#pragma unroll
        for (int n = 0; n < 4; ++n) {
          long col = ccol0 + n * 16;
          C[row * ldc + col] = f2bf(acc[m][n][j] + bias[col]);
        }
      }
  } else if constexpr (EPI == EPI_EXPSUM) {
    u16* C = (u16*)Cv + (long)g * sC;
    float* lr = lrow + (long)g * sL;
#pragma unroll
    for (int m = 0; m < 4; ++m)
#pragma unroll
      for (int j = 0; j < 4; ++j) {
        long row = crow0 + m * 16 + j;
        float rs = 0.f;
#pragma unroll
        for (int n = 0; n < 4; ++n) {
          float e = expf(acc[m][n][j] * alpha);
          C[row * ldc + ccol0 + n * 16] = f2bf(e);
          rs += e;
        }
        rs += __shfl_xor(rs, 1);
        rs += __shfl_xor(rs, 2);
        rs += __shfl_xor(rs, 4);
        rs += __shfl_xor(rs, 8);
        if (fr == 0) atomicAdd(&lr[row], rs);
      }
  } else if constexpr (EPI == EPI_STF32) {
    float* C = (float*)Cv + (long)g * sC;
#pragma unroll
    for (int m = 0; m < 4; ++m)
#pragma unroll
      for (int j = 0; j < 4; ++j) {
        long row = crow0 + m * 16 + j;
#pragma unroll
        for (int n = 0; n < 4; ++n)
          C[row * ldc + ccol0 + n * 16] = acc[m][n][j] * alpha;
      }
  } else {  // EPI_ADDDIV: out += acc / lrow[row]
    float* C = (float*)Cv + (long)g * sC;
    const float* lr = lrow + (long)g * sL;
#pragma unroll
    for (int m = 0; m < 4; ++m)
#pragma unroll
      for (int j = 0; j < 4; ++j) {
        long row = crow0 + m * 16 + j;
        float rl = 1.0f / lr[row];
#pragma unroll
        for (int n = 0; n < 4; ++n) {
          long idx = row * ldc + ccol0 + n * 16;
          C[idx] += acc[m][n][j] * rl;
        }
      }
  }
}

// transpose q/k/v slices: in qkv[g][2048][1536] col block which*512 -> out[(g*3+which)][512][2048]
__global__ __launch_bounds__(256)
void transpose_qkv(const u16* __restrict__ qkv, u16* __restrict__ tout)
{
  const int z = blockIdx.z;
  const int g = z / 3, which = z % 3;
  const u16* in = qkv + (long)g * NTOK * QKVD + which * EDIM;
  u16* out = tout + (long)z * EDIM * NTOK;
  __shared__ u16 tile[64][68];
  const long r0 = (long)blockIdx.x * 64;  // token rows
  const long c0 = (long)blockIdx.y * 64;  // feature cols
  const int t = threadIdx.x;
  const int tr = t >> 4;
  const int tc = (t & 15) * 4;
#pragma unroll
  for (int i = 0; i < 4; ++i) {
    u16x4 v = *(const u16x4*)&in[(r0 + tr + i * 16) * QKVD + c0 + tc];
    *(u16x4*)&tile[tr + i * 16][tc] = v;
  }
  __syncthreads();
  const int on4 = (t & 15) * 4;
  const int od = t >> 4;
#pragma unroll
  for (int i = 0; i < 4; ++i) {
    int d = od + i * 16;
    u16x4 v;
    v[0] = tile[on4 + 0][d];
    v[1] = tile[on4 + 1][d];
    v[2] = tile[on4 + 2][d];
    v[3] = tile[on4 + 3][d];
    *(u16x4*)&out[(c0 + d) * NTOK + r0 + on4] = v;
  }
}

__global__ __launch_bounds__(256)
void cast_bf16_vec(const float* __restrict__ in, u16* __restrict__ out, long n8)
{
  long i = (long)blockIdx.x * 256 + threadIdx.x;
  if (i >= n8) return;
  const float4* p = (const float4*)(in + i * 8);
  float4 a = p[0], b = p[1];
  u16x8 r;
  r[0] = f2bf(a.x); r[1] = f2bf(a.y); r[2] = f2bf(a.z); r[3] = f2bf(a.w);
  r[4] = f2bf(b.x); r[5] = f2bf(b.y); r[6] = f2bf(b.z); r[7] = f2bf(b.w);
  *(u16x8*)(out + i * 8) = r;
}

// w [512][1536] f32 -> wT [1536][512] bf16 (runs once, tiny)
__global__ __launch_bounds__(256)
void cast_wT(const float* __restrict__ w, u16* __restrict__ wT)
{
  int idx = blockIdx.x * 256 + threadIdx.x;
  int c = idx >> 9;
  int d = idx & 511;
  wT[idx] = f2bf(w[d * QKVD + c]);
}

// row softmax over 512 floats, one wave per row, out bf16 (normalized)
__global__ __launch_bounds__(256)
void softmax_rows512(const float* __restrict__ S, u16* __restrict__ P)
{
  long row = (long)blockIdx.x * 4 + (threadIdx.x >> 6);
  int lane = threadIdx.x & 63;
  const float* s = S + row * 512;
  u16* p = P + row * 512;
  f32x4 a = *(const f32x4*)(s + lane * 4);
  f32x4 b = *(const f32x4*)(s + 256 + lane * 4);
  float m = fmaxf(fmaxf(fmaxf(a[0], a[1]), fmaxf(a[2], a[3])),
                  fmaxf(fmaxf(b[0], b[1]), fmaxf(b[2], b[3])));
  for (int o = 32; o; o >>= 1) m = fmaxf(m, __shfl_xor(m, o));
  float e[8];
  e[0] = expf(a[0] - m); e[1] = expf(a[1] - m);
  e[2] = expf(a[2] - m); e[3] = expf(a[3] - m);
  e[4] = expf(b[0] - m); e[5] = expf(b[1] - m);
  e[6] = expf(b[2] - m); e[7] = expf(b[3] - m);
  float sum = e[0] + e[1] + e[2] + e[3] + e[4] + e[5] + e[6] + e[7];
  for (int o = 32; o; o >>= 1) sum += __shfl_xor(sum, o);
  float r = 1.f / sum;
  u16x4 o1, o2;
  o1[0] = f2bf(e[0] * r); o1[1] = f2bf(e[1] * r);
  o1[2] = f2bf(e[2] * r); o1[3] = f2bf(e[3] * r);
  o2[0] = f2bf(e[4] * r); o2[1] = f2bf(e[5] * r);
  o2[2] = f2bf(e[6] * r); o2[3] = f2bf(e[7] * r);
  *(u16x4*)(p + lane * 4) = o1;
  *(u16x4*)(p + 256 + lane * 4) = o2;
}

extern "C" void kernel_launch(void* const* d_in, const int* in_sizes, int n_in,
                              void* d_out, int out_size, void* d_ws, size_t ws_size,
                              hipStream_t stream)
{
  const float* x    = (const float*)d_in[0];
  const float* w    = (const float*)d_in[1];
  const float* bias = (const float*)d_in[2];
  float* out = (float*)d_out;

  // workspace carve; G = batches in flight (8 -> ~200MB, falls back if ws small)
  size_t offs[8];
  long G = 8;
  auto carve = [&](long g) -> size_t {
    size_t sizes[8] = {
      (size_t)(QKVD * EDIM * 2),        // 0 wT
      (size_t)(g * NTOK * EDIM * 2),    // 1 xb
      (size_t)(g * NTOK * QKVD * 2),    // 2 qkv
      (size_t)(g * 3 * EDIM * NTOK * 2),// 3 tbuf (qT,kT,vT)
      (size_t)(g * NTOK * NTOK * 2),    // 4 Prow
      (size_t)(g * NTOK * 4),           // 5 lrow
      (size_t)(g * EDIM * EDIM * 4),    // 6 Scol
      (size_t)(g * EDIM * EDIM * 2),    // 7 Pcol
    };
    size_t o = 0;
    for (int i = 0; i < 8; ++i) { offs[i] = o; o += (sizes[i] + 255) & ~(size_t)255; }
    return o;
  };
  while (G > 1 && carve(G) > ws_size) G >>= 1;
  if (carve(G) > ws_size) return;  // cannot run in given workspace

  char* wsb = (char*)d_ws;
  u16*   wT   = (u16*)(wsb + offs[0]);
  u16*   xb   = (u16*)(wsb + offs[1]);
  u16*   qkv  = (u16*)(wsb + offs[2]);
  u16*   tbuf = (u16*)(wsb + offs[3]);
  u16*   Prow = (u16*)(wsb + offs[4]);
  float* lrow = (float*)(wsb + offs[5]);
  float* Scol = (float*)(wsb + offs[6]);
  u16*   Pcol = (u16*)(wsb + offs[7]);

  const float RS = 0.044194173824159216f;  // 1/sqrt(512)

  cast_wT<<<dim3((int)((QKVD * EDIM) / 256)), 256, 0, stream>>>(w, wT);

  const long nch = BATCH / G;
  for (long ch = 0; ch < nch; ++ch) {
    const float* xch = x + ch * G * NTOK * EDIM;
    float* och = out + ch * G * NTOK * EDIM;

    cast_bf16_vec<<<dim3((int)(G * NTOK * EDIM / 8 / 256)), 256, 0, stream>>>(
        xch, xb, G * NTOK * EDIM / 8);

    // qkv = xb @ wT^T + bias  -> bf16 [g][2048][1536]
    gemm_bt<EPI_BIAS><<<dim3((int)(QKVD / 128), (int)(NTOK / 128), (int)G), 256, 0, stream>>>(
        xb, EDIM, NTOK * EDIM, wT, EDIM, 0,
        qkv, QKVD, NTOK * QKVD, bias, nullptr, 0, 1.f, (int)EDIM);

    transpose_qkv<<<dim3((int)(NTOK / 64), (int)(EDIM / 64), (int)(G * 3)), 256, 0, stream>>>(qkv, tbuf);

    hipMemsetAsync(lrow, 0, G * NTOK * 4, stream);

    // Prow = exp(q k^T / sqrt(E)) (unnormalized), lrow = row sums
    gemm_bt<EPI_EXPSUM><<<dim3((int)(NTOK / 128), (int)(NTOK / 128), (int)G), 256, 0, stream>>>(
        qkv, QKVD, NTOK * QKVD, qkv + EDIM, QKVD, NTOK * QKVD,
        Prow, NTOK, NTOK * NTOK, nullptr, lrow, NTOK, RS, (int)EDIM);

    // Scol = (q^T k) / sqrt(E)  [512x512]
    gemm_bt<EPI_STF32><<<dim3((int)(EDIM / 128), (int)(EDIM / 128), (int)G), 256, 0, stream>>>(
        tbuf, NTOK, 3 * EDIM * NTOK, tbuf + EDIM * NTOK, NTOK, 3 * EDIM * NTOK,
        Scol, EDIM, EDIM * EDIM, nullptr, nullptr, 0, RS, (int)NTOK);

    softmax_rows512<<<dim3((int)(G * EDIM / 4)), 256, 0, stream>>>(Scol, Pcol);

    // out = v @ Pcol^T   (column attention)
    gemm_bt<EPI_STF32><<<dim3((int)(EDIM / 128), (int)(NTOK / 128), (int)G), 256, 0, stream>>>(
        qkv + 2 * EDIM, QKVD, NTOK * QKVD, Pcol, EDIM, EDIM * EDIM,
        och, EDIM, NTOK * EDIM, nullptr, nullptr, 0, 1.f, (int)EDIM);

    // out += (Prow @ vT^T) / lrow   (row attention)
    gemm_bt<EPI_ADDDIV><<<dim3((int)(EDIM / 128), (int)(NTOK / 128), (int)G), 256, 0, stream>>>(
        Prow, NTOK, NTOK * NTOK, tbuf + 2 * EDIM * NTOK, NTOK, 3 * EDIM * NTOK,
        och, EDIM, NTOK * EDIM, nullptr, lrow, NTOK, 1.f, (int)NTOK);
  }
  (void)in_sizes; (void)n_in; (void)out_size;
}